// Round 4
// baseline (951.838 us; speedup 1.0000x reference)
//
#include <hip/hip_runtime.h>
#include <hip/hip_bf16.h>
#include <cstdint>

#define HID 64
#define NPG 100
#define BSHIFT 7
#define BMASK ((1 << BSHIFT) - 1)
#define BCAP 4096

typedef short bf16x8 __attribute__((ext_vector_type(8)));
typedef float f32x4 __attribute__((ext_vector_type(4)));

__device__ __forceinline__ unsigned short bf16_rn(float f) {
    union { float f; unsigned u; } c; c.f = f;
    unsigned r = c.u + 0x7fffu + ((c.u >> 16) & 1u);
    return (unsigned short)(r >> 16);
}
__device__ __forceinline__ float bf16_f(unsigned short h) {
    union { unsigned u; float f; } c; c.u = ((unsigned)h) << 16;
    return c.f;
}

// decoder chain-graph degree: in-edges into position p come from p-1,p-2,p+1,p+2 (valid ones), +1 self-loop
__device__ __forceinline__ float dinvdec(int p) {
    int d = (p >= 1) + (p >= 2) + (p <= NPG - 2) + (p <= NPG - 3);
    return rsqrtf((float)(d + 1));
}

// ---------------- CSR build ----------------

__global__ void zero_int_kernel(int* __restrict__ p, int n) {
    int i = blockIdx.x * 256 + threadIdx.x;
    if (i < n) p[i] = 0;
}

// one pass: per-node degree count + bucket-binned packed edge append.
// bcur is padded: one counter per 64B line (stride 16 ints).
__global__ void bin_kernel(const int* __restrict__ src, const int* __restrict__ dst,
                           int* __restrict__ cnt, int* __restrict__ bcur,
                           int* __restrict__ binned, int E) {
    int e = blockIdx.x * 256 + threadIdx.x;
    if (e >= E) return;
    int s = src[e], d = dst[e];
    atomicAdd(&cnt[d], 1);
    int b = d >> BSHIFT;
    int pos = atomicAdd(&bcur[b * 16], 1);
    if (pos < BCAP) binned[(size_t)b * BCAP + pos] = (s << BSHIFT) | (d & BMASK);
}

__global__ void dinv_kernel(const int* __restrict__ cnt, float* __restrict__ dinv, int N) {
    int i = blockIdx.x * 256 + threadIdx.x;
    if (i < N) dinv[i] = rsqrtf((float)cnt[i] + 1.0f);
}

// block scans 2048 ints (256 thr x 8)
__global__ __launch_bounds__(256) void scan1_kernel(const int* __restrict__ cnt,
                                                    int* __restrict__ row_ptr,
                                                    int* __restrict__ partials, int N) {
    __shared__ int sd[256];
    int tid = threadIdx.x;
    int base = blockIdx.x * 2048 + tid * 8;
    int v[8];
    int s = 0;
#pragma unroll
    for (int j = 0; j < 8; j++) {
        int i = base + j;
        int t = (i < N) ? cnt[i] : 0;
        v[j] = t; s += t;
    }
    sd[tid] = s;
    __syncthreads();
    for (int off = 1; off < 256; off <<= 1) {
        int t = (tid >= off) ? sd[tid - off] : 0;
        __syncthreads();
        sd[tid] += t;
        __syncthreads();
    }
    int run = sd[tid] - s;  // exclusive within block
#pragma unroll
    for (int j = 0; j < 8; j++) {
        int i = base + j;
        if (i < N) row_ptr[i] = run;
        run += v[j];
    }
    if (tid == 0) partials[blockIdx.x] = sd[255];
}

__global__ void scan2_kernel(int* __restrict__ partials, int nb) {
    __shared__ int sd[128];
    int tid = threadIdx.x;
    int v = (tid < nb) ? partials[tid] : 0;
    sd[tid] = v;
    __syncthreads();
    for (int off = 1; off < 128; off <<= 1) {
        int t = (tid >= off) ? sd[tid - off] : 0;
        __syncthreads();
        sd[tid] += t;
        __syncthreads();
    }
    if (tid < nb) partials[tid] = sd[tid] - v;
}

__global__ void scan3_kernel(int* __restrict__ row_ptr, const int* __restrict__ partials,
                             int N, int E) {
    int base = blockIdx.x * 2048 + threadIdx.x * 8;
    int add = partials[blockIdx.x];
#pragma unroll
    for (int j = 0; j < 8; j++) {
        int i = base + j;
        if (i < N) row_ptr[i] += add;
    }
    if (blockIdx.x == 0 && threadIdx.x == 0) row_ptr[N] = E;
}

// one block per bucket: scatter bucket's packed edges into the (L2-resident) CSR window.
// per-dst cursors live in LDS (block owns the bucket exclusively).
__global__ __launch_bounds__(256) void fill2_kernel(const int* __restrict__ bcur,
                                                    const int* __restrict__ binned,
                                                    const int* __restrict__ row_ptr,
                                                    int* __restrict__ csr_src, int NBUK) {
    __shared__ int lc[1 << BSHIFT];
    int b = blockIdx.x;
    if (threadIdx.x < (1 << BSHIFT)) lc[threadIdx.x] = 0;
    __syncthreads();
    int nb = bcur[b * 16];
    if (nb > BCAP) nb = BCAP;
    const int* bb = binned + (size_t)b * BCAP;
    const int base = b << BSHIFT;
    for (int i = threadIdx.x; i < nb; i += 256) {
        int v = bb[i];
        int s = v >> BSHIFT;
        int dl = v & BMASK;
        int pos = row_ptr[base + dl] + atomicAdd(&lc[dl], 1);
        csr_src[pos] = s;
    }
}

// ---------------- MFMA GEMM (bf16 hi/lo split, fp32-grade accuracy) ----------------
template <int K, int N, int SCALE_MODE, bool BIAS>
__global__ __launch_bounds__(256, 2) void mfma_gemm(const float* __restrict__ A,
                                                    const float* __restrict__ W,
                                                    const float* __restrict__ bias,
                                                    const float* __restrict__ rowscale,
                                                    float* __restrict__ out, int M) {
    constexpr int KP = K + 8;
    constexpr int NT = N / 16;
    constexpr int KS = K / 32;
    __shared__ unsigned short Wt[2][N][KP];
    const int tid = threadIdx.x;

    for (int idx = tid; idx < K * N; idx += 256) {
        float w = W[idx];
        int k = idx / N, n = idx % N;  // N is pow2
        unsigned short h = bf16_rn(w);
        Wt[0][n][k] = h;
        Wt[1][n][k] = bf16_rn(w - bf16_f(h));
    }
    __syncthreads();

    const int lane = tid & 63;
    const int l15 = lane & 15;
    const int lg = lane >> 4;  // 0..3
    const int nstrips = M / 16;
    const int wglobal = blockIdx.x * 4 + (tid >> 6);
    const int wtotal = gridDim.x * 4;

    float cur[KS * 8], nxt[KS * 8];

    auto loadA = [&](int s, float* dstv) {
        const float* arow = A + (size_t)(s * 16 + l15) * K + lg * 8;
#pragma unroll
        for (int ks = 0; ks < KS; ks++) {
            float4 a = *(const float4*)(arow + ks * 32);
            float4 b = *(const float4*)(arow + ks * 32 + 4);
            dstv[ks * 8 + 0] = a.x; dstv[ks * 8 + 1] = a.y;
            dstv[ks * 8 + 2] = a.z; dstv[ks * 8 + 3] = a.w;
            dstv[ks * 8 + 4] = b.x; dstv[ks * 8 + 5] = b.y;
            dstv[ks * 8 + 6] = b.z; dstv[ks * 8 + 7] = b.w;
        }
    };

    int s = wglobal;
    if (s < nstrips) loadA(s, cur);
    for (; s < nstrips; s += wtotal) {
        int sn = s + wtotal;
        if (sn < nstrips) loadA(sn, nxt);

        f32x4 acc[NT];
#pragma unroll
        for (int t = 0; t < NT; t++) acc[t] = f32x4{0.f, 0.f, 0.f, 0.f};

#pragma unroll
        for (int ks = 0; ks < KS; ks++) {
            bf16x8 ah, al;
#pragma unroll
            for (int j = 0; j < 8; j++) {
                float v = cur[ks * 8 + j];
                unsigned short h = bf16_rn(v);
                ah[j] = (short)h;
                al[j] = (short)bf16_rn(v - bf16_f(h));
            }
            const int k0 = ks * 32 + lg * 8;
#pragma unroll
            for (int t = 0; t < NT; t++) {
                int n = t * 16 + l15;
                bf16x8 bh = *(const bf16x8*)&Wt[0][n][k0];
                bf16x8 bl = *(const bf16x8*)&Wt[1][n][k0];
                acc[t] = __builtin_amdgcn_mfma_f32_16x16x32_bf16(ah, bh, acc[t], 0, 0, 0);
                acc[t] = __builtin_amdgcn_mfma_f32_16x16x32_bf16(ah, bl, acc[t], 0, 0, 0);
                acc[t] = __builtin_amdgcn_mfma_f32_16x16x32_bf16(al, bh, acc[t], 0, 0, 0);
            }
        }

#pragma unroll
        for (int r = 0; r < 4; r++) {
            int row = s * 16 + lg * 4 + r;
            float scale = 1.0f;
            if (SCALE_MODE == 1) scale = rowscale[row];
            if (SCALE_MODE == 2) scale = dinvdec(row % NPG);
#pragma unroll
            for (int t = 0; t < NT; t++) {
                float o = acc[t][r] * scale;
                if (BIAS) o += bias[t * 16 + l15];
                out[(size_t)row * N + t * 16 + l15] = o;
            }
        }
#pragma unroll
        for (int i = 0; i < KS * 8; i++) cur[i] = nxt[i];
    }
}

// ---------------- encoder aggregation (gather over CSR) ----------------
// 16 lanes/row (float4/lane = 256B/gather); 16-deep index+gather pipeline.
__global__ __launch_bounds__(256) void agg_kernel(const float* __restrict__ g,
                                                  const int* __restrict__ row_ptr,
                                                  const int* __restrict__ csr_src,
                                                  const float* __restrict__ dinv,
                                                  const float* __restrict__ bias,
                                                  float* __restrict__ out, int N, int do_relu) {
    const int tid = threadIdx.x;
    const int sub = tid >> 4;
    const int lg = tid & 15;
    const int row = blockIdx.x * 16 + sub;
    if (row >= N) return;

    const float4* g4 = (const float4*)g;
    float4 acc = g4[(size_t)row * 16 + lg];

    const int s = row_ptr[row];
    const int e = row_ptr[row + 1];
    int j = s;

#define ACC4(vv) do { acc.x += vv.x; acc.y += vv.y; acc.z += vv.z; acc.w += vv.w; } while (0)

    for (; j + 16 <= e; j += 16) {
        int idx[16];
#pragma unroll
        for (int t = 0; t < 16; t++) idx[t] = csr_src[j + t];
        float4 v[16];
#pragma unroll
        for (int t = 0; t < 16; t++) v[t] = g4[(size_t)idx[t] * 16 + lg];
#pragma unroll
        for (int t = 0; t < 16; t++) ACC4(v[t]);
    }
    for (; j + 8 <= e; j += 8) {
        int idx[8];
#pragma unroll
        for (int t = 0; t < 8; t++) idx[t] = csr_src[j + t];
        float4 v[8];
#pragma unroll
        for (int t = 0; t < 8; t++) v[t] = g4[(size_t)idx[t] * 16 + lg];
#pragma unroll
        for (int t = 0; t < 8; t++) ACC4(v[t]);
    }
    for (; j + 2 <= e; j += 2) {
        int i0 = csr_src[j + 0], i1 = csr_src[j + 1];
        float4 v0 = g4[(size_t)i0 * 16 + lg];
        float4 v1 = g4[(size_t)i1 * 16 + lg];
        ACC4(v0); ACC4(v1);
    }
    if (j < e) {
        int i0 = csr_src[j];
        float4 v0 = g4[(size_t)i0 * 16 + lg];
        ACC4(v0);
    }
#undef ACC4

    const float d = dinv[row];
    float4 bv = ((const float4*)bias)[lg];
    float4 o;
    o.x = d * acc.x + bv.x;
    o.y = d * acc.y + bv.y;
    o.z = d * acc.z + bv.z;
    o.w = d * acc.w + bv.w;
    if (do_relu) {
        o.x = fmaxf(o.x, 0.0f); o.y = fmaxf(o.y, 0.0f);
        o.z = fmaxf(o.z, 0.0f); o.w = fmaxf(o.w, 0.0f);
    }
    ((float4*)out)[(size_t)row * 16 + lg] = o;
}

// ---------------- pooling: mean over each graph's 100 rows ----------------
__global__ void pool_kernel(const float* __restrict__ h, float* __restrict__ emb, int NG) {
    int wid = (blockIdx.x * 256 + threadIdx.x) >> 6;
    int lane = threadIdx.x & 63;
    if (wid >= NG) return;
    const float* base = h + (size_t)wid * NPG * HID + lane;
    float acc = 0.0f;
    for (int i = 0; i < NPG; i++) acc += base[i * HID];
    emb[wid * HID + lane] = acc * (1.0f / NPG);
}

// ---------------- decoder init: t = (emb@Wt + bt) @ W1, one wave per graph ----------------
__global__ void decinit_kernel(const float* __restrict__ emb, const float* __restrict__ Wt,
                               const float* __restrict__ bt, const float* __restrict__ W1,
                               float* __restrict__ t, int NG) {
    int wid = (blockIdx.x * 256 + threadIdx.x) >> 6;
    int lane = threadIdx.x & 63;
    if (wid >= NG) return;
    float e = emb[wid * HID + lane];
    float acc = bt[lane];
    for (int k = 0; k < HID; k++) acc += __shfl(e, k) * Wt[k * HID + lane];
    float tv = 0.0f;
    for (int k = 0; k < HID; k++) tv += __shfl(acc, k) * W1[k * HID + lane];
    t[wid * HID + lane] = tv;
}

// ---------------- decoder layer 1: z1[i] = relu(t[graph]*s[pos] + b1) ----------------
__global__ void z1_kernel(const float* __restrict__ t, const float* __restrict__ b1,
                          float* __restrict__ out, int N) {
    int i4 = blockIdx.x * 256 + threadIdx.x;
    if (i4 >= N * (HID / 4)) return;
    int row = i4 >> 4, c4 = i4 & 15;
    int gph = row / NPG;
    int p = row - gph * NPG;
    float dp = dinvdec(p);
    float qs = dp;
    if (p >= 1) qs += dinvdec(p - 1);
    if (p >= 2) qs += dinvdec(p - 2);
    if (p <= NPG - 2) qs += dinvdec(p + 1);
    if (p <= NPG - 3) qs += dinvdec(p + 2);
    float s = dp * qs;
    float4 tv = ((const float4*)t)[gph * (HID / 4) + c4];
    float4 bv = ((const float4*)b1)[c4];
    float4 o;
    o.x = fmaxf(s * tv.x + bv.x, 0.0f);
    o.y = fmaxf(s * tv.y + bv.y, 0.0f);
    o.z = fmaxf(s * tv.z + bv.z, 0.0f);
    o.w = fmaxf(s * tv.w + bv.w, 0.0f);
    ((float4*)out)[i4] = o;
}

// ---------------- decoder stencil layers (one block per graph) ----------------
__global__ __launch_bounds__(256) void stencil_kernel(const float* __restrict__ g,
                                                      const float* __restrict__ bias,
                                                      float* __restrict__ out, int NG) {
    __shared__ float gs[NPG * HID];
    int gph = blockIdx.x;
    const float4* src = (const float4*)(g + (size_t)gph * NPG * HID);
    for (int idx = threadIdx.x; idx < NPG * HID / 4; idx += 256)
        ((float4*)gs)[idx] = src[idx];
    __syncthreads();
    int c = threadIdx.x & 63;
    for (int p = threadIdx.x >> 6; p < NPG; p += 4) {
        float acc = gs[p * HID + c];
        if (p >= 1) acc += gs[(p - 1) * HID + c];
        if (p >= 2) acc += gs[(p - 2) * HID + c];
        if (p <= NPG - 2) acc += gs[(p + 1) * HID + c];
        if (p <= NPG - 3) acc += gs[(p + 2) * HID + c];
        float v = dinvdec(p) * acc + bias[c];
        v = fmaxf(v, 0.0f);
        out[(size_t)(gph * NPG + p) * HID + c] = v;
    }
}

// ---------------- launch ----------------

extern "C" void kernel_launch(void* const* d_in, const int* in_sizes, int n_in,
                              void* d_out, int out_size, void* d_ws, size_t ws_size,
                              hipStream_t stream) {
    const float* x      = (const float*)d_in[0];
    const int*   edge   = (const int*)d_in[1];
    const float* enc_W1 = (const float*)d_in[3];
    const float* enc_b1 = (const float*)d_in[4];
    const float* enc_W2 = (const float*)d_in[5];
    const float* enc_b2 = (const float*)d_in[6];
    const float* enc_W3 = (const float*)d_in[7];
    const float* enc_b3 = (const float*)d_in[8];
    const float* dec_Wt = (const float*)d_in[9];
    const float* dec_bt = (const float*)d_in[10];
    const float* dec_W1 = (const float*)d_in[11];
    const float* dec_b1 = (const float*)d_in[12];
    const float* dec_W2 = (const float*)d_in[13];
    const float* dec_b2 = (const float*)d_in[14];
    const float* dec_W3 = (const float*)d_in[15];
    const float* dec_b3 = (const float*)d_in[16];
    const float* out_W  = (const float*)d_in[17];
    const float* out_b  = (const float*)d_in[18];

    const int N  = in_sizes[0] / 128;  // 200000
    const int E  = in_sizes[1] / 2;    // 3200000
    const int NG = N / NPG;            // 2000
    const int NBUK = (N + BMASK) >> BSHIFT;  // 1563
    const int* esrc = edge;
    const int* edst = edge + E;

    char* w = (char*)d_ws;
    auto alloc = [&](size_t bytes) -> void* {
        void* p = (void*)w;
        w += (bytes + 255) & ~(size_t)255;
        return p;
    };
    float* bufA    = (float*)alloc((size_t)N * HID * 4);
    int*   csr     = (int*)alloc((size_t)E * 4);
    int*   row_ptr = (int*)alloc((size_t)(N + 1) * 4);
    int*   cnt     = (int*)alloc((size_t)N * 4);
    float* dinv    = (float*)alloc((size_t)N * 4);
    int*   partials= (int*)alloc(1024);
    float* emb     = (float*)alloc((size_t)NG * HID * 4);
    float* tbuf    = (float*)alloc((size_t)NG * HID * 4);
    int*   bcur    = (int*)alloc((size_t)NBUK * 16 * 4);
    int*   binned  = (int*)alloc((size_t)NBUK * BCAP * 4);

    float* B1 = (float*)d_out;                    // first half of d_out as scratch
    float* B2 = (float*)d_out + (size_t)N * HID;  // second half

    const int NB = (N + 2047) / 2048;
    const int GB = 1024;  // gemm blocks (4 waves each)

    // CSR build (binned two-phase scatter)
    zero_int_kernel<<<(N + 255) / 256, 256, 0, stream>>>(cnt, N);
    zero_int_kernel<<<(NBUK * 16 + 255) / 256, 256, 0, stream>>>(bcur, NBUK * 16);
    bin_kernel<<<(E + 255) / 256, 256, 0, stream>>>(esrc, edst, cnt, bcur, binned, E);
    dinv_kernel<<<(N + 255) / 256, 256, 0, stream>>>(cnt, dinv, N);
    scan1_kernel<<<NB, 256, 0, stream>>>(cnt, row_ptr, partials, N);
    scan2_kernel<<<1, 128, 0, stream>>>(partials, NB);
    scan3_kernel<<<NB, 256, 0, stream>>>(row_ptr, partials, N, E);
    fill2_kernel<<<NBUK, 256, 0, stream>>>(bcur, binned, row_ptr, csr, NBUK);

    // encoder
    mfma_gemm<128, 64, 1, false><<<GB, 256, 0, stream>>>(x, enc_W1, nullptr, dinv, bufA, N);
    agg_kernel<<<(N + 15) / 16, 256, 0, stream>>>(bufA, row_ptr, csr, dinv, enc_b1, B1, N, 1);
    mfma_gemm<64, 64, 1, false><<<GB, 256, 0, stream>>>(B1, enc_W2, nullptr, dinv, bufA, N);
    agg_kernel<<<(N + 15) / 16, 256, 0, stream>>>(bufA, row_ptr, csr, dinv, enc_b2, B1, N, 1);
    mfma_gemm<64, 64, 1, false><<<GB, 256, 0, stream>>>(B1, enc_W3, nullptr, dinv, bufA, N);
    agg_kernel<<<(N + 15) / 16, 256, 0, stream>>>(bufA, row_ptr, csr, dinv, enc_b3, B1, N, 0);

    // pooling + decoder head
    pool_kernel<<<(NG * 64 + 255) / 256, 256, 0, stream>>>(B1, emb, NG);
    decinit_kernel<<<(NG * 64 + 255) / 256, 256, 0, stream>>>(emb, dec_Wt, dec_bt, dec_W1, tbuf, NG);
    z1_kernel<<<(N * 16 + 255) / 256, 256, 0, stream>>>(tbuf, dec_b1, B1, N);

    // decoder stencil layers
    mfma_gemm<64, 64, 2, false><<<GB, 256, 0, stream>>>(B1, dec_W2, nullptr, nullptr, bufA, N);
    stencil_kernel<<<NG, 256, 0, stream>>>(bufA, dec_b2, B1, NG);
    mfma_gemm<64, 64, 2, false><<<GB, 256, 0, stream>>>(B1, dec_W3, nullptr, nullptr, B2, N);
    stencil_kernel<<<NG, 256, 0, stream>>>(B2, dec_b3, bufA, NG);

    // output projection
    mfma_gemm<64, 128, 0, true><<<GB, 256, 0, stream>>>(bufA, out_W, out_b, nullptr,
                                                        (float*)d_out, N);
}

// Round 5
// 691.962 us; speedup vs baseline: 1.3756x; 1.3756x over previous
//
#include <hip/hip_runtime.h>
#include <hip/hip_bf16.h>
#include <cstdint>

#define HID 64
#define NPG 100

// coarse buckets for CSR build: 1024 dsts per bucket
#define CSHIFT 10
#define CMASK ((1 << CSHIFT) - 1)
#define CAP 56          // LDS slots per bin per tile (λ≈42, spill ~1%)
#define TILE 8192       // edges per phase-1 block
#define SLOT 32768      // staging ints per bucket (mean ~16.6k, 2x slack)

typedef short bf16x8 __attribute__((ext_vector_type(8)));
typedef float f32x4 __attribute__((ext_vector_type(4)));

__device__ __forceinline__ unsigned short bf16_rn(float f) {
    union { float f; unsigned u; } c; c.f = f;
    unsigned r = c.u + 0x7fffu + ((c.u >> 16) & 1u);
    return (unsigned short)(r >> 16);
}
__device__ __forceinline__ float bf16_f(unsigned short h) {
    union { unsigned u; float f; } c; c.u = ((unsigned)h) << 16;
    return c.f;
}

// decoder chain-graph degree: in-edges into position p come from p-1,p-2,p+1,p+2 (valid ones), +1 self-loop
__device__ __forceinline__ float dinvdec(int p) {
    int d = (p >= 1) + (p >= 2) + (p <= NPG - 2) + (p <= NPG - 3);
    return rsqrtf((float)(d + 1));
}

// ---------------- CSR build (LDS-binned, no cross-XCD line sharing) ----------------

__global__ void zero_int_kernel(int* __restrict__ p, int n) {
    int i = blockIdx.x * 256 + threadIdx.x;
    if (i < n) p[i] = 0;
}

// Phase 1: block-private tile -> LDS bins -> chunked flush (one padded atomic per bin).
__global__ __launch_bounds__(256) void bin1_kernel(const int* __restrict__ src,
                                                   const int* __restrict__ dst,
                                                   int* __restrict__ gcur,
                                                   int* __restrict__ stage,
                                                   int E, int nbin) {
    __shared__ int bins[256][CAP];
    __shared__ int bcnt[256];
    const int tid = threadIdx.x;
    bcnt[tid] = 0;
    __syncthreads();

    const int e0 = blockIdx.x * TILE;
    const int cnt = min(TILE, E - e0);
    for (int i = tid; i < cnt; i += 256) {
        int s = src[e0 + i], d = dst[e0 + i];
        int b = d >> CSHIFT;
        int v = (s << CSHIFT) | (d & CMASK);
        int pos = atomicAdd(&bcnt[b], 1);
        if (pos < CAP) {
            bins[b][pos] = v;
        } else {  // rare spill: private 4-slot chunk, -1 pads
            int g = atomicAdd(&gcur[b * 16], 4);
            int* sp = stage + (size_t)b * SLOT + g;
            sp[0] = v; sp[1] = -1; sp[2] = -1; sp[3] = -1;
        }
    }
    __syncthreads();

    if (tid < nbin) {
        int c = min(bcnt[tid], CAP);
        int r = (c + 3) & ~3;
        if (r > 0) {
            int base = atomicAdd(&gcur[tid * 16], r);
            int* dstp = stage + (size_t)tid * SLOT + base;
            for (int j = 0; j < r; j += 4) {
                int4 v;
                v.x = (j + 0 < c) ? bins[tid][j + 0] : -1;
                v.y = (j + 1 < c) ? bins[tid][j + 1] : -1;
                v.z = (j + 2 < c) ? bins[tid][j + 2] : -1;
                v.w = (j + 3 < c) ? bins[tid][j + 3] : -1;
                *(int4*)(dstp + j) = v;
            }
        }
    }
}

// Phase 2a: per-bucket degree count (LDS) -> coalesced cnt + dinv writes.
__global__ __launch_bounds__(256) void bin_count_kernel(const int* __restrict__ gcur,
                                                        const int* __restrict__ stage,
                                                        int* __restrict__ cntg,
                                                        float* __restrict__ dinvg, int N) {
    __shared__ int lc[1 << CSHIFT];
    const int b = blockIdx.x;
    for (int j = threadIdx.x; j < (1 << CSHIFT); j += 256) lc[j] = 0;
    __syncthreads();
    const int len = gcur[b * 16];
    const int* sp = stage + (size_t)b * SLOT;
    for (int i = threadIdx.x; i < len; i += 256) {
        int v = sp[i];
        if (v >= 0) atomicAdd(&lc[v & CMASK], 1);
    }
    __syncthreads();
    const int d0 = b << CSHIFT;
    for (int j = threadIdx.x; j < (1 << CSHIFT); j += 256) {
        int d = d0 + j;
        if (d < N) {
            int c = lc[j];
            cntg[d] = c;
            dinvg[d] = rsqrtf((float)c + 1.0f);
        }
    }
}

// block scans 2048 ints (256 thr x 8)
__global__ __launch_bounds__(256) void scan1_kernel(const int* __restrict__ cnt,
                                                    int* __restrict__ row_ptr,
                                                    int* __restrict__ partials, int N) {
    __shared__ int sd[256];
    int tid = threadIdx.x;
    int base = blockIdx.x * 2048 + tid * 8;
    int v[8];
    int s = 0;
#pragma unroll
    for (int j = 0; j < 8; j++) {
        int i = base + j;
        int t = (i < N) ? cnt[i] : 0;
        v[j] = t; s += t;
    }
    sd[tid] = s;
    __syncthreads();
    for (int off = 1; off < 256; off <<= 1) {
        int t = (tid >= off) ? sd[tid - off] : 0;
        __syncthreads();
        sd[tid] += t;
        __syncthreads();
    }
    int run = sd[tid] - s;  // exclusive within block
#pragma unroll
    for (int j = 0; j < 8; j++) {
        int i = base + j;
        if (i < N) row_ptr[i] = run;
        run += v[j];
    }
    if (tid == 0) partials[blockIdx.x] = sd[255];
}

__global__ void scan2_kernel(int* __restrict__ partials, int nb) {
    __shared__ int sd[128];
    int tid = threadIdx.x;
    int v = (tid < nb) ? partials[tid] : 0;
    sd[tid] = v;
    __syncthreads();
    for (int off = 1; off < 128; off <<= 1) {
        int t = (tid >= off) ? sd[tid - off] : 0;
        __syncthreads();
        sd[tid] += t;
        __syncthreads();
    }
    if (tid < nb) partials[tid] = sd[tid] - v;
}

__global__ void scan3_kernel(int* __restrict__ row_ptr, const int* __restrict__ partials,
                             int N, int E) {
    int base = blockIdx.x * 2048 + threadIdx.x * 8;
    int add = partials[blockIdx.x];
#pragma unroll
    for (int j = 0; j < 8; j++) {
        int i = base + j;
        if (i < N) row_ptr[i] += add;
    }
    if (blockIdx.x == 0 && threadIdx.x == 0) row_ptr[N] = E;
}

// Phase 2b: per-bucket scatter into exclusive L2-resident CSR window, LDS cursors.
__global__ __launch_bounds__(256) void bin_fill_kernel(const int* __restrict__ gcur,
                                                       const int* __restrict__ stage,
                                                       const int* __restrict__ row_ptr,
                                                       int* __restrict__ csr_src, int N) {
    __shared__ int cur[1 << CSHIFT];
    __shared__ int rp[1 << CSHIFT];
    const int b = blockIdx.x;
    const int d0 = b << CSHIFT;
    for (int j = threadIdx.x; j < (1 << CSHIFT); j += 256) {
        cur[j] = 0;
        int d = d0 + j;
        rp[j] = (d < N) ? row_ptr[d] : 0;
    }
    __syncthreads();
    const int len = gcur[b * 16];
    const int* sp = stage + (size_t)b * SLOT;
    for (int i = threadIdx.x; i < len; i += 256) {
        int v = sp[i];
        if (v >= 0) {
            int dl = v & CMASK;
            int pos = rp[dl] + atomicAdd(&cur[dl], 1);
            csr_src[pos] = v >> CSHIFT;
        }
    }
}

// ---------------- MFMA GEMM (bf16 hi/lo split, fp32-grade accuracy) ----------------
template <int K, int N, int SCALE_MODE, bool BIAS>
__global__ __launch_bounds__(256, 2) void mfma_gemm(const float* __restrict__ A,
                                                    const float* __restrict__ W,
                                                    const float* __restrict__ bias,
                                                    const float* __restrict__ rowscale,
                                                    float* __restrict__ out, int M) {
    constexpr int KP = K + 8;
    constexpr int NT = N / 16;
    constexpr int KS = K / 32;
    __shared__ unsigned short Wt[2][N][KP];
    const int tid = threadIdx.x;

    for (int idx = tid; idx < K * N; idx += 256) {
        float w = W[idx];
        int k = idx / N, n = idx % N;  // N is pow2
        unsigned short h = bf16_rn(w);
        Wt[0][n][k] = h;
        Wt[1][n][k] = bf16_rn(w - bf16_f(h));
    }
    __syncthreads();

    const int lane = tid & 63;
    const int l15 = lane & 15;
    const int lg = lane >> 4;  // 0..3
    const int nstrips = M / 16;
    const int wglobal = blockIdx.x * 4 + (tid >> 6);
    const int wtotal = gridDim.x * 4;

    float cur[KS * 8], nxt[KS * 8];

    auto loadA = [&](int s, float* dstv) {
        const float* arow = A + (size_t)(s * 16 + l15) * K + lg * 8;
#pragma unroll
        for (int ks = 0; ks < KS; ks++) {
            float4 a = *(const float4*)(arow + ks * 32);
            float4 b = *(const float4*)(arow + ks * 32 + 4);
            dstv[ks * 8 + 0] = a.x; dstv[ks * 8 + 1] = a.y;
            dstv[ks * 8 + 2] = a.z; dstv[ks * 8 + 3] = a.w;
            dstv[ks * 8 + 4] = b.x; dstv[ks * 8 + 5] = b.y;
            dstv[ks * 8 + 6] = b.z; dstv[ks * 8 + 7] = b.w;
        }
    };

    int s = wglobal;
    if (s < nstrips) loadA(s, cur);
    for (; s < nstrips; s += wtotal) {
        int sn = s + wtotal;
        if (sn < nstrips) loadA(sn, nxt);

        f32x4 acc[NT];
#pragma unroll
        for (int t = 0; t < NT; t++) acc[t] = f32x4{0.f, 0.f, 0.f, 0.f};

#pragma unroll
        for (int ks = 0; ks < KS; ks++) {
            bf16x8 ah, al;
#pragma unroll
            for (int j = 0; j < 8; j++) {
                float v = cur[ks * 8 + j];
                unsigned short h = bf16_rn(v);
                ah[j] = (short)h;
                al[j] = (short)bf16_rn(v - bf16_f(h));
            }
            const int k0 = ks * 32 + lg * 8;
#pragma unroll
            for (int t = 0; t < NT; t++) {
                int n = t * 16 + l15;
                bf16x8 bh = *(const bf16x8*)&Wt[0][n][k0];
                bf16x8 bl = *(const bf16x8*)&Wt[1][n][k0];
                acc[t] = __builtin_amdgcn_mfma_f32_16x16x32_bf16(ah, bh, acc[t], 0, 0, 0);
                acc[t] = __builtin_amdgcn_mfma_f32_16x16x32_bf16(ah, bl, acc[t], 0, 0, 0);
                acc[t] = __builtin_amdgcn_mfma_f32_16x16x32_bf16(al, bh, acc[t], 0, 0, 0);
            }
        }

#pragma unroll
        for (int r = 0; r < 4; r++) {
            int row = s * 16 + lg * 4 + r;
            float scale = 1.0f;
            if (SCALE_MODE == 1) scale = rowscale[row];
            if (SCALE_MODE == 2) scale = dinvdec(row % NPG);
#pragma unroll
            for (int t = 0; t < NT; t++) {
                float o = acc[t][r] * scale;
                if (BIAS) o += bias[t * 16 + l15];
                out[(size_t)row * N + t * 16 + l15] = o;
            }
        }
#pragma unroll
        for (int i = 0; i < KS * 8; i++) cur[i] = nxt[i];
    }
}

// ---------------- encoder aggregation (gather over CSR) ----------------
// 16 lanes/row (float4/lane = 256B/gather); 16-deep index+gather pipeline.
__global__ __launch_bounds__(256) void agg_kernel(const float* __restrict__ g,
                                                  const int* __restrict__ row_ptr,
                                                  const int* __restrict__ csr_src,
                                                  const float* __restrict__ dinv,
                                                  const float* __restrict__ bias,
                                                  float* __restrict__ out, int N, int do_relu) {
    const int tid = threadIdx.x;
    const int sub = tid >> 4;
    const int lg = tid & 15;
    const int row = blockIdx.x * 16 + sub;
    if (row >= N) return;

    const float4* g4 = (const float4*)g;
    float4 acc = g4[(size_t)row * 16 + lg];

    const int s = row_ptr[row];
    const int e = row_ptr[row + 1];
    int j = s;

#define ACC4(vv) do { acc.x += vv.x; acc.y += vv.y; acc.z += vv.z; acc.w += vv.w; } while (0)

    for (; j + 16 <= e; j += 16) {
        int idx[16];
#pragma unroll
        for (int t = 0; t < 16; t++) idx[t] = csr_src[j + t];
        float4 v[16];
#pragma unroll
        for (int t = 0; t < 16; t++) v[t] = g4[(size_t)idx[t] * 16 + lg];
#pragma unroll
        for (int t = 0; t < 16; t++) ACC4(v[t]);
    }
    for (; j + 8 <= e; j += 8) {
        int idx[8];
#pragma unroll
        for (int t = 0; t < 8; t++) idx[t] = csr_src[j + t];
        float4 v[8];
#pragma unroll
        for (int t = 0; t < 8; t++) v[t] = g4[(size_t)idx[t] * 16 + lg];
#pragma unroll
        for (int t = 0; t < 8; t++) ACC4(v[t]);
    }
    for (; j + 2 <= e; j += 2) {
        int i0 = csr_src[j + 0], i1 = csr_src[j + 1];
        float4 v0 = g4[(size_t)i0 * 16 + lg];
        float4 v1 = g4[(size_t)i1 * 16 + lg];
        ACC4(v0); ACC4(v1);
    }
    if (j < e) {
        int i0 = csr_src[j];
        float4 v0 = g4[(size_t)i0 * 16 + lg];
        ACC4(v0);
    }
#undef ACC4

    const float d = dinv[row];
    float4 bv = ((const float4*)bias)[lg];
    float4 o;
    o.x = d * acc.x + bv.x;
    o.y = d * acc.y + bv.y;
    o.z = d * acc.z + bv.z;
    o.w = d * acc.w + bv.w;
    if (do_relu) {
        o.x = fmaxf(o.x, 0.0f); o.y = fmaxf(o.y, 0.0f);
        o.z = fmaxf(o.z, 0.0f); o.w = fmaxf(o.w, 0.0f);
    }
    ((float4*)out)[(size_t)row * 16 + lg] = o;
}

// ---------------- pooling: mean over each graph's 100 rows ----------------
__global__ void pool_kernel(const float* __restrict__ h, float* __restrict__ emb, int NG) {
    int wid = (blockIdx.x * 256 + threadIdx.x) >> 6;
    int lane = threadIdx.x & 63;
    if (wid >= NG) return;
    const float* base = h + (size_t)wid * NPG * HID + lane;
    float acc = 0.0f;
    for (int i = 0; i < NPG; i++) acc += base[i * HID];
    emb[wid * HID + lane] = acc * (1.0f / NPG);
}

// ---------------- decoder init: t = (emb@Wt + bt) @ W1, one wave per graph ----------------
__global__ void decinit_kernel(const float* __restrict__ emb, const float* __restrict__ Wt,
                               const float* __restrict__ bt, const float* __restrict__ W1,
                               float* __restrict__ t, int NG) {
    int wid = (blockIdx.x * 256 + threadIdx.x) >> 6;
    int lane = threadIdx.x & 63;
    if (wid >= NG) return;
    float e = emb[wid * HID + lane];
    float acc = bt[lane];
    for (int k = 0; k < HID; k++) acc += __shfl(e, k) * Wt[k * HID + lane];
    float tv = 0.0f;
    for (int k = 0; k < HID; k++) tv += __shfl(acc, k) * W1[k * HID + lane];
    t[wid * HID + lane] = tv;
}

// ---------------- decoder layer 1: z1[i] = relu(t[graph]*s[pos] + b1) ----------------
__global__ void z1_kernel(const float* __restrict__ t, const float* __restrict__ b1,
                          float* __restrict__ out, int N) {
    int i4 = blockIdx.x * 256 + threadIdx.x;
    if (i4 >= N * (HID / 4)) return;
    int row = i4 >> 4, c4 = i4 & 15;
    int gph = row / NPG;
    int p = row - gph * NPG;
    float dp = dinvdec(p);
    float qs = dp;
    if (p >= 1) qs += dinvdec(p - 1);
    if (p >= 2) qs += dinvdec(p - 2);
    if (p <= NPG - 2) qs += dinvdec(p + 1);
    if (p <= NPG - 3) qs += dinvdec(p + 2);
    float s = dp * qs;
    float4 tv = ((const float4*)t)[gph * (HID / 4) + c4];
    float4 bv = ((const float4*)b1)[c4];
    float4 o;
    o.x = fmaxf(s * tv.x + bv.x, 0.0f);
    o.y = fmaxf(s * tv.y + bv.y, 0.0f);
    o.z = fmaxf(s * tv.z + bv.z, 0.0f);
    o.w = fmaxf(s * tv.w + bv.w, 0.0f);
    ((float4*)out)[i4] = o;
}

// ---------------- decoder stencil layers (one block per graph) ----------------
__global__ __launch_bounds__(256) void stencil_kernel(const float* __restrict__ g,
                                                      const float* __restrict__ bias,
                                                      float* __restrict__ out, int NG) {
    __shared__ float gs[NPG * HID];
    int gph = blockIdx.x;
    const float4* src = (const float4*)(g + (size_t)gph * NPG * HID);
    for (int idx = threadIdx.x; idx < NPG * HID / 4; idx += 256)
        ((float4*)gs)[idx] = src[idx];
    __syncthreads();
    int c = threadIdx.x & 63;
    for (int p = threadIdx.x >> 6; p < NPG; p += 4) {
        float acc = gs[p * HID + c];
        if (p >= 1) acc += gs[(p - 1) * HID + c];
        if (p >= 2) acc += gs[(p - 2) * HID + c];
        if (p <= NPG - 2) acc += gs[(p + 1) * HID + c];
        if (p <= NPG - 3) acc += gs[(p + 2) * HID + c];
        float v = dinvdec(p) * acc + bias[c];
        v = fmaxf(v, 0.0f);
        out[(size_t)(gph * NPG + p) * HID + c] = v;
    }
}

// ---------------- launch ----------------

extern "C" void kernel_launch(void* const* d_in, const int* in_sizes, int n_in,
                              void* d_out, int out_size, void* d_ws, size_t ws_size,
                              hipStream_t stream) {
    const float* x      = (const float*)d_in[0];
    const int*   edge   = (const int*)d_in[1];
    const float* enc_W1 = (const float*)d_in[3];
    const float* enc_b1 = (const float*)d_in[4];
    const float* enc_W2 = (const float*)d_in[5];
    const float* enc_b2 = (const float*)d_in[6];
    const float* enc_W3 = (const float*)d_in[7];
    const float* enc_b3 = (const float*)d_in[8];
    const float* dec_Wt = (const float*)d_in[9];
    const float* dec_bt = (const float*)d_in[10];
    const float* dec_W1 = (const float*)d_in[11];
    const float* dec_b1 = (const float*)d_in[12];
    const float* dec_W2 = (const float*)d_in[13];
    const float* dec_b2 = (const float*)d_in[14];
    const float* dec_W3 = (const float*)d_in[15];
    const float* dec_b3 = (const float*)d_in[16];
    const float* out_W  = (const float*)d_in[17];
    const float* out_b  = (const float*)d_in[18];

    const int N  = in_sizes[0] / 128;  // 200000
    const int E  = in_sizes[1] / 2;    // 3200000
    const int NG = N / NPG;            // 2000
    const int NBIN = (N + CMASK) >> CSHIFT;  // 196
    const int* esrc = edge;
    const int* edst = edge + E;

    char* w = (char*)d_ws;
    auto alloc = [&](size_t bytes) -> void* {
        void* p = (void*)w;
        w += (bytes + 255) & ~(size_t)255;
        return p;
    };
    float* bufA    = (float*)alloc((size_t)N * HID * 4);
    int*   csr     = (int*)alloc((size_t)E * 4);
    int*   row_ptr = (int*)alloc((size_t)(N + 1) * 4);
    int*   cnt     = (int*)alloc((size_t)N * 4);
    float* dinv    = (float*)alloc((size_t)N * 4);
    int*   partials= (int*)alloc(1024);
    float* emb     = (float*)alloc((size_t)NG * HID * 4);
    float* tbuf    = (float*)alloc((size_t)NG * HID * 4);
    int*   gcur    = (int*)alloc((size_t)NBIN * 16 * 4);
    int*   stage   = (int*)alloc((size_t)NBIN * SLOT * 4);

    float* B1 = (float*)d_out;                    // first half of d_out as scratch
    float* B2 = (float*)d_out + (size_t)N * HID;  // second half

    const int NB = (N + 2047) / 2048;
    const int GB = 1024;  // gemm blocks (4 waves each)

    // CSR build: LDS-binned two-phase, no random global atomics
    zero_int_kernel<<<(NBIN * 16 + 255) / 256, 256, 0, stream>>>(gcur, NBIN * 16);
    bin1_kernel<<<(E + TILE - 1) / TILE, 256, 0, stream>>>(esrc, edst, gcur, stage, E, NBIN);
    bin_count_kernel<<<NBIN, 256, 0, stream>>>(gcur, stage, cnt, dinv, N);
    scan1_kernel<<<NB, 256, 0, stream>>>(cnt, row_ptr, partials, N);
    scan2_kernel<<<1, 128, 0, stream>>>(partials, NB);
    scan3_kernel<<<NB, 256, 0, stream>>>(row_ptr, partials, N, E);
    bin_fill_kernel<<<NBIN, 256, 0, stream>>>(gcur, stage, row_ptr, csr, N);

    // encoder
    mfma_gemm<128, 64, 1, false><<<GB, 256, 0, stream>>>(x, enc_W1, nullptr, dinv, bufA, N);
    agg_kernel<<<(N + 15) / 16, 256, 0, stream>>>(bufA, row_ptr, csr, dinv, enc_b1, B1, N, 1);
    mfma_gemm<64, 64, 1, false><<<GB, 256, 0, stream>>>(B1, enc_W2, nullptr, dinv, bufA, N);
    agg_kernel<<<(N + 15) / 16, 256, 0, stream>>>(bufA, row_ptr, csr, dinv, enc_b2, B1, N, 1);
    mfma_gemm<64, 64, 1, false><<<GB, 256, 0, stream>>>(B1, enc_W3, nullptr, dinv, bufA, N);
    agg_kernel<<<(N + 15) / 16, 256, 0, stream>>>(bufA, row_ptr, csr, dinv, enc_b3, B1, N, 0);

    // pooling + decoder head
    pool_kernel<<<(NG * 64 + 255) / 256, 256, 0, stream>>>(B1, emb, NG);
    decinit_kernel<<<(NG * 64 + 255) / 256, 256, 0, stream>>>(emb, dec_Wt, dec_bt, dec_W1, tbuf, NG);
    z1_kernel<<<(N * 16 + 255) / 256, 256, 0, stream>>>(tbuf, dec_b1, B1, N);

    // decoder stencil layers
    mfma_gemm<64, 64, 2, false><<<GB, 256, 0, stream>>>(B1, dec_W2, nullptr, nullptr, bufA, N);
    stencil_kernel<<<NG, 256, 0, stream>>>(bufA, dec_b2, B1, NG);
    mfma_gemm<64, 64, 2, false><<<GB, 256, 0, stream>>>(B1, dec_W3, nullptr, nullptr, B2, N);
    stencil_kernel<<<NG, 256, 0, stream>>>(B2, dec_b3, bufA, NG);

    // output projection
    mfma_gemm<64, 128, 0, true><<<GB, 256, 0, stream>>>(bufA, out_W, out_b, nullptr,
                                                        (float*)d_out, N);
}

// Round 6
// 542.787 us; speedup vs baseline: 1.7536x; 1.2748x over previous
//
#include <hip/hip_runtime.h>
#include <hip/hip_bf16.h>
#include <cstdint>

#define HID 64
#define NPG 100

// coarse buckets for CSR build: 1024 dsts per bucket
#define CSHIFT 10
#define CMASK ((1 << CSHIFT) - 1)
#define CAP 56          // LDS slots per bin per tile (λ≈42, spill ~1%)
#define TILE 8192       // edges per phase-1 block
#define SLOT 32768      // staging ints per bucket (mean ~16.6k, 2x slack)

typedef short bf16x8 __attribute__((ext_vector_type(8)));
typedef float f32x4 __attribute__((ext_vector_type(4)));

__device__ __forceinline__ unsigned short bf16_rn(float f) {
    union { float f; unsigned u; } c; c.f = f;
    unsigned r = c.u + 0x7fffu + ((c.u >> 16) & 1u);
    return (unsigned short)(r >> 16);
}
__device__ __forceinline__ float bf16_f(unsigned short h) {
    union { unsigned u; float f; } c; c.u = ((unsigned)h) << 16;
    return c.f;
}
__device__ __forceinline__ float f_lo(unsigned u) {
    union { unsigned u; float f; } c; c.u = u << 16;
    return c.f;
}
__device__ __forceinline__ float f_hi(unsigned u) {
    union { unsigned u; float f; } c; c.u = u & 0xffff0000u;
    return c.f;
}

// decoder chain-graph degree
__device__ __forceinline__ float dinvdec(int p) {
    int d = (p >= 1) + (p >= 2) + (p <= NPG - 2) + (p <= NPG - 3);
    return rsqrtf((float)(d + 1));
}

// ---------------- CSR build (LDS-binned, no cross-XCD line sharing) ----------------

__global__ void zero_int_kernel(int* __restrict__ p, int n) {
    int i = blockIdx.x * 256 + threadIdx.x;
    if (i < n) p[i] = 0;
}

// Phase 1: block-private tile -> LDS bins -> chunked flush (one padded atomic per bin).
__global__ __launch_bounds__(256) void bin1_kernel(const int* __restrict__ src,
                                                   const int* __restrict__ dst,
                                                   int* __restrict__ gcur,
                                                   int* __restrict__ stage,
                                                   int E, int nbin) {
    __shared__ int bins[256][CAP];
    __shared__ int bcnt[256];
    const int tid = threadIdx.x;
    bcnt[tid] = 0;
    __syncthreads();

    const int e0 = blockIdx.x * TILE;
    const int cnt = min(TILE, E - e0);
    for (int i = tid; i < cnt; i += 256) {
        int s = src[e0 + i], d = dst[e0 + i];
        int b = d >> CSHIFT;
        int v = (s << CSHIFT) | (d & CMASK);
        int pos = atomicAdd(&bcnt[b], 1);
        if (pos < CAP) {
            bins[b][pos] = v;
        } else {  // rare spill: private 4-slot chunk, -1 pads
            int g = atomicAdd(&gcur[b * 16], 4);
            int* sp = stage + (size_t)b * SLOT + g;
            sp[0] = v; sp[1] = -1; sp[2] = -1; sp[3] = -1;
        }
    }
    __syncthreads();

    if (tid < nbin) {
        int c = min(bcnt[tid], CAP);
        int r = (c + 3) & ~3;
        if (r > 0) {
            int base = atomicAdd(&gcur[tid * 16], r);
            int* dstp = stage + (size_t)tid * SLOT + base;
            for (int j = 0; j < r; j += 4) {
                int4 v;
                v.x = (j + 0 < c) ? bins[tid][j + 0] : -1;
                v.y = (j + 1 < c) ? bins[tid][j + 1] : -1;
                v.z = (j + 2 < c) ? bins[tid][j + 2] : -1;
                v.w = (j + 3 < c) ? bins[tid][j + 3] : -1;
                *(int4*)(dstp + j) = v;
            }
        }
    }
}

// Phase 2a: per-bucket degree count (LDS) -> coalesced cnt + dinv writes.
__global__ __launch_bounds__(256) void bin_count_kernel(const int* __restrict__ gcur,
                                                        const int* __restrict__ stage,
                                                        int* __restrict__ cntg,
                                                        float* __restrict__ dinvg, int N) {
    __shared__ int lc[1 << CSHIFT];
    const int b = blockIdx.x;
    for (int j = threadIdx.x; j < (1 << CSHIFT); j += 256) lc[j] = 0;
    __syncthreads();
    const int len = gcur[b * 16];
    const int* sp = stage + (size_t)b * SLOT;
    for (int i = threadIdx.x; i < len; i += 256) {
        int v = sp[i];
        if (v >= 0) atomicAdd(&lc[v & CMASK], 1);
    }
    __syncthreads();
    const int d0 = b << CSHIFT;
    for (int j = threadIdx.x; j < (1 << CSHIFT); j += 256) {
        int d = d0 + j;
        if (d < N) {
            int c = lc[j];
            cntg[d] = c;
            dinvg[d] = rsqrtf((float)c + 1.0f);
        }
    }
}

// block scans 2048 ints (256 thr x 8)
__global__ __launch_bounds__(256) void scan1_kernel(const int* __restrict__ cnt,
                                                    int* __restrict__ row_ptr,
                                                    int* __restrict__ partials, int N) {
    __shared__ int sd[256];
    int tid = threadIdx.x;
    int base = blockIdx.x * 2048 + tid * 8;
    int v[8];
    int s = 0;
#pragma unroll
    for (int j = 0; j < 8; j++) {
        int i = base + j;
        int t = (i < N) ? cnt[i] : 0;
        v[j] = t; s += t;
    }
    sd[tid] = s;
    __syncthreads();
    for (int off = 1; off < 256; off <<= 1) {
        int t = (tid >= off) ? sd[tid - off] : 0;
        __syncthreads();
        sd[tid] += t;
        __syncthreads();
    }
    int run = sd[tid] - s;  // exclusive within block
#pragma unroll
    for (int j = 0; j < 8; j++) {
        int i = base + j;
        if (i < N) row_ptr[i] = run;
        run += v[j];
    }
    if (tid == 0) partials[blockIdx.x] = sd[255];
}

__global__ void scan2_kernel(int* __restrict__ partials, int nb) {
    __shared__ int sd[128];
    int tid = threadIdx.x;
    int v = (tid < nb) ? partials[tid] : 0;
    sd[tid] = v;
    __syncthreads();
    for (int off = 1; off < 128; off <<= 1) {
        int t = (tid >= off) ? sd[tid - off] : 0;
        __syncthreads();
        sd[tid] += t;
        __syncthreads();
    }
    if (tid < nb) partials[tid] = sd[tid] - v;
}

__global__ void scan3_kernel(int* __restrict__ row_ptr, const int* __restrict__ partials,
                             int N, int E) {
    int base = blockIdx.x * 2048 + threadIdx.x * 8;
    int add = partials[blockIdx.x];
#pragma unroll
    for (int j = 0; j < 8; j++) {
        int i = base + j;
        if (i < N) row_ptr[i] += add;
    }
    if (blockIdx.x == 0 && threadIdx.x == 0) row_ptr[N] = E;
}

// Phase 2b: per-bucket scatter into exclusive L2-resident CSR window, LDS cursors.
__global__ __launch_bounds__(256) void bin_fill_kernel(const int* __restrict__ gcur,
                                                       const int* __restrict__ stage,
                                                       const int* __restrict__ row_ptr,
                                                       int* __restrict__ csr_src, int N) {
    __shared__ int cur[1 << CSHIFT];
    __shared__ int rp[1 << CSHIFT];
    const int b = blockIdx.x;
    const int d0 = b << CSHIFT;
    for (int j = threadIdx.x; j < (1 << CSHIFT); j += 256) {
        cur[j] = 0;
        int d = d0 + j;
        rp[j] = (d < N) ? row_ptr[d] : 0;
    }
    __syncthreads();
    const int len = gcur[b * 16];
    const int* sp = stage + (size_t)b * SLOT;
    for (int i = threadIdx.x; i < len; i += 256) {
        int v = sp[i];
        if (v >= 0) {
            int dl = v & CMASK;
            int pos = rp[dl] + atomicAdd(&cur[dl], 1);
            csr_src[pos] = v >> CSHIFT;
        }
    }
}

// ---------------- MFMA GEMM (bf16 hi/lo split, fp32-grade accuracy) ----------------
// OBF16: write packed bf16 output (for the gather-heavy encoder agg input).
template <int K, int N, int SCALE_MODE, bool BIAS, bool OBF16>
__global__ __launch_bounds__(256, 2) void mfma_gemm(const float* __restrict__ A,
                                                    const float* __restrict__ W,
                                                    const float* __restrict__ bias,
                                                    const float* __restrict__ rowscale,
                                                    float* __restrict__ out, int M) {
    constexpr int KP = K + 8;
    constexpr int NT = N / 16;
    constexpr int KS = K / 32;
    __shared__ unsigned short Wt[2][N][KP];
    const int tid = threadIdx.x;

    for (int idx = tid; idx < K * N; idx += 256) {
        float w = W[idx];
        int k = idx / N, n = idx % N;  // N is pow2
        unsigned short h = bf16_rn(w);
        Wt[0][n][k] = h;
        Wt[1][n][k] = bf16_rn(w - bf16_f(h));
    }
    __syncthreads();

    const int lane = tid & 63;
    const int l15 = lane & 15;
    const int lg = lane >> 4;  // 0..3
    const int nstrips = M / 16;
    const int wglobal = blockIdx.x * 4 + (tid >> 6);
    const int wtotal = gridDim.x * 4;

    float cur[KS * 8], nxt[KS * 8];

    auto loadA = [&](int s, float* dstv) {
        const float* arow = A + (size_t)(s * 16 + l15) * K + lg * 8;
#pragma unroll
        for (int ks = 0; ks < KS; ks++) {
            float4 a = *(const float4*)(arow + ks * 32);
            float4 b = *(const float4*)(arow + ks * 32 + 4);
            dstv[ks * 8 + 0] = a.x; dstv[ks * 8 + 1] = a.y;
            dstv[ks * 8 + 2] = a.z; dstv[ks * 8 + 3] = a.w;
            dstv[ks * 8 + 4] = b.x; dstv[ks * 8 + 5] = b.y;
            dstv[ks * 8 + 6] = b.z; dstv[ks * 8 + 7] = b.w;
        }
    };

    int s = wglobal;
    if (s < nstrips) loadA(s, cur);
    for (; s < nstrips; s += wtotal) {
        int sn = s + wtotal;
        if (sn < nstrips) loadA(sn, nxt);

        f32x4 acc[NT];
#pragma unroll
        for (int t = 0; t < NT; t++) acc[t] = f32x4{0.f, 0.f, 0.f, 0.f};

#pragma unroll
        for (int ks = 0; ks < KS; ks++) {
            bf16x8 ah, al;
#pragma unroll
            for (int j = 0; j < 8; j++) {
                float v = cur[ks * 8 + j];
                unsigned short h = bf16_rn(v);
                ah[j] = (short)h;
                al[j] = (short)bf16_rn(v - bf16_f(h));
            }
            const int k0 = ks * 32 + lg * 8;
#pragma unroll
            for (int t = 0; t < NT; t++) {
                int n = t * 16 + l15;
                bf16x8 bh = *(const bf16x8*)&Wt[0][n][k0];
                bf16x8 bl = *(const bf16x8*)&Wt[1][n][k0];
                acc[t] = __builtin_amdgcn_mfma_f32_16x16x32_bf16(ah, bh, acc[t], 0, 0, 0);
                acc[t] = __builtin_amdgcn_mfma_f32_16x16x32_bf16(ah, bl, acc[t], 0, 0, 0);
                acc[t] = __builtin_amdgcn_mfma_f32_16x16x32_bf16(al, bh, acc[t], 0, 0, 0);
            }
        }

#pragma unroll
        for (int r = 0; r < 4; r++) {
            int row = s * 16 + lg * 4 + r;
            float scale = 1.0f;
            if (SCALE_MODE == 1) scale = rowscale[row];
            if (SCALE_MODE == 2) scale = dinvdec(row % NPG);
#pragma unroll
            for (int t = 0; t < NT; t++) {
                float o = acc[t][r] * scale;
                if (BIAS) o += bias[t * 16 + l15];
                if (OBF16) {
                    ((unsigned short*)out)[(size_t)row * N + t * 16 + l15] = bf16_rn(o);
                } else {
                    out[(size_t)row * N + t * 16 + l15] = o;
                }
            }
        }
#pragma unroll
        for (int i = 0; i < KS * 8; i++) cur[i] = nxt[i];
    }
}

// ---------------- encoder aggregation (gather over CSR, bf16 rows) ----------------
// g is packed bf16 [N][64] = 128B/row. 8 lanes/row (uint4 = 8 bf16 per lane),
// 32 rows per 256-thread block; 16-deep index+gather pipeline; fp32 accumulate.
__global__ __launch_bounds__(256) void agg_kernel(const unsigned int* __restrict__ g,
                                                  const int* __restrict__ row_ptr,
                                                  const int* __restrict__ csr_src,
                                                  const float* __restrict__ dinv,
                                                  const float* __restrict__ bias,
                                                  float* __restrict__ out, int N, int do_relu) {
    const int tid = threadIdx.x;
    const int sub = tid >> 3;        // 0..31: row within block
    const int lg = tid & 7;          // 16B group within row
    const int row = blockIdx.x * 32 + sub;
    if (row >= N) return;

    const uint4* g4 = (const uint4*)g;
    float acc[8] = {};

#define ACC8(vv) do { \
    acc[0] += f_lo(vv.x); acc[1] += f_hi(vv.x); \
    acc[2] += f_lo(vv.y); acc[3] += f_hi(vv.y); \
    acc[4] += f_lo(vv.z); acc[5] += f_hi(vv.z); \
    acc[6] += f_lo(vv.w); acc[7] += f_hi(vv.w); } while (0)

    {   // self term
        uint4 v = g4[(size_t)row * 8 + lg];
        ACC8(v);
    }

    const int s = row_ptr[row];
    const int e = row_ptr[row + 1];
    int j = s;

    for (; j + 16 <= e; j += 16) {
        int idx[16];
#pragma unroll
        for (int t = 0; t < 16; t++) idx[t] = csr_src[j + t];
        uint4 v[16];
#pragma unroll
        for (int t = 0; t < 16; t++) v[t] = g4[(size_t)idx[t] * 8 + lg];
#pragma unroll
        for (int t = 0; t < 16; t++) ACC8(v[t]);
    }
    for (; j + 4 <= e; j += 4) {
        int idx[4];
#pragma unroll
        for (int t = 0; t < 4; t++) idx[t] = csr_src[j + t];
        uint4 v[4];
#pragma unroll
        for (int t = 0; t < 4; t++) v[t] = g4[(size_t)idx[t] * 8 + lg];
#pragma unroll
        for (int t = 0; t < 4; t++) ACC8(v[t]);
    }
    for (; j < e; j++) {
        uint4 v = g4[(size_t)csr_src[j] * 8 + lg];
        ACC8(v);
    }
#undef ACC8

    const float d = dinv[row];
    float4 b0 = ((const float4*)bias)[lg * 2];
    float4 b1 = ((const float4*)bias)[lg * 2 + 1];
    float4 o0, o1;
    o0.x = d * acc[0] + b0.x; o0.y = d * acc[1] + b0.y;
    o0.z = d * acc[2] + b0.z; o0.w = d * acc[3] + b0.w;
    o1.x = d * acc[4] + b1.x; o1.y = d * acc[5] + b1.y;
    o1.z = d * acc[6] + b1.z; o1.w = d * acc[7] + b1.w;
    if (do_relu) {
        o0.x = fmaxf(o0.x, 0.0f); o0.y = fmaxf(o0.y, 0.0f);
        o0.z = fmaxf(o0.z, 0.0f); o0.w = fmaxf(o0.w, 0.0f);
        o1.x = fmaxf(o1.x, 0.0f); o1.y = fmaxf(o1.y, 0.0f);
        o1.z = fmaxf(o1.z, 0.0f); o1.w = fmaxf(o1.w, 0.0f);
    }
    float4* orow = (float4*)(out + (size_t)row * HID + lg * 8);
    orow[0] = o0;
    orow[1] = o1;
}

// ---------------- pooling: mean over each graph's 100 rows ----------------
__global__ void pool_kernel(const float* __restrict__ h, float* __restrict__ emb, int NG) {
    int wid = (blockIdx.x * 256 + threadIdx.x) >> 6;
    int lane = threadIdx.x & 63;
    if (wid >= NG) return;
    const float* base = h + (size_t)wid * NPG * HID + lane;
    float acc = 0.0f;
    for (int i = 0; i < NPG; i++) acc += base[i * HID];
    emb[wid * HID + lane] = acc * (1.0f / NPG);
}

// ---------------- decoder init: t = (emb@Wt + bt) @ W1, one wave per graph ----------------
__global__ void decinit_kernel(const float* __restrict__ emb, const float* __restrict__ Wt,
                               const float* __restrict__ bt, const float* __restrict__ W1,
                               float* __restrict__ t, int NG) {
    int wid = (blockIdx.x * 256 + threadIdx.x) >> 6;
    int lane = threadIdx.x & 63;
    if (wid >= NG) return;
    float e = emb[wid * HID + lane];
    float acc = bt[lane];
    for (int k = 0; k < HID; k++) acc += __shfl(e, k) * Wt[k * HID + lane];
    float tv = 0.0f;
    for (int k = 0; k < HID; k++) tv += __shfl(acc, k) * W1[k * HID + lane];
    t[wid * HID + lane] = tv;
}

// ---------------- decoder layer 1: z1[i] = relu(t[graph]*s[pos] + b1) ----------------
__global__ void z1_kernel(const float* __restrict__ t, const float* __restrict__ b1,
                          float* __restrict__ out, int N) {
    int i4 = blockIdx.x * 256 + threadIdx.x;
    if (i4 >= N * (HID / 4)) return;
    int row = i4 >> 4, c4 = i4 & 15;
    int gph = row / NPG;
    int p = row - gph * NPG;
    float dp = dinvdec(p);
    float qs = dp;
    if (p >= 1) qs += dinvdec(p - 1);
    if (p >= 2) qs += dinvdec(p - 2);
    if (p <= NPG - 2) qs += dinvdec(p + 1);
    if (p <= NPG - 3) qs += dinvdec(p + 2);
    float s = dp * qs;
    float4 tv = ((const float4*)t)[gph * (HID / 4) + c4];
    float4 bv = ((const float4*)b1)[c4];
    float4 o;
    o.x = fmaxf(s * tv.x + bv.x, 0.0f);
    o.y = fmaxf(s * tv.y + bv.y, 0.0f);
    o.z = fmaxf(s * tv.z + bv.z, 0.0f);
    o.w = fmaxf(s * tv.w + bv.w, 0.0f);
    ((float4*)out)[i4] = o;
}

// ---------------- decoder stencil layers (one block per graph) ----------------
__global__ __launch_bounds__(256) void stencil_kernel(const float* __restrict__ g,
                                                      const float* __restrict__ bias,
                                                      float* __restrict__ out, int NG) {
    __shared__ float gs[NPG * HID];
    int gph = blockIdx.x;
    const float4* src = (const float4*)(g + (size_t)gph * NPG * HID);
    for (int idx = threadIdx.x; idx < NPG * HID / 4; idx += 256)
        ((float4*)gs)[idx] = src[idx];
    __syncthreads();
    int c = threadIdx.x & 63;
    for (int p = threadIdx.x >> 6; p < NPG; p += 4) {
        float acc = gs[p * HID + c];
        if (p >= 1) acc += gs[(p - 1) * HID + c];
        if (p >= 2) acc += gs[(p - 2) * HID + c];
        if (p <= NPG - 2) acc += gs[(p + 1) * HID + c];
        if (p <= NPG - 3) acc += gs[(p + 2) * HID + c];
        float v = dinvdec(p) * acc + bias[c];
        v = fmaxf(v, 0.0f);
        out[(size_t)(gph * NPG + p) * HID + c] = v;
    }
}

// ---------------- launch ----------------

extern "C" void kernel_launch(void* const* d_in, const int* in_sizes, int n_in,
                              void* d_out, int out_size, void* d_ws, size_t ws_size,
                              hipStream_t stream) {
    const float* x      = (const float*)d_in[0];
    const int*   edge   = (const int*)d_in[1];
    const float* enc_W1 = (const float*)d_in[3];
    const float* enc_b1 = (const float*)d_in[4];
    const float* enc_W2 = (const float*)d_in[5];
    const float* enc_b2 = (const float*)d_in[6];
    const float* enc_W3 = (const float*)d_in[7];
    const float* enc_b3 = (const float*)d_in[8];
    const float* dec_Wt = (const float*)d_in[9];
    const float* dec_bt = (const float*)d_in[10];
    const float* dec_W1 = (const float*)d_in[11];
    const float* dec_b1 = (const float*)d_in[12];
    const float* dec_W2 = (const float*)d_in[13];
    const float* dec_b2 = (const float*)d_in[14];
    const float* dec_W3 = (const float*)d_in[15];
    const float* dec_b3 = (const float*)d_in[16];
    const float* out_W  = (const float*)d_in[17];
    const float* out_b  = (const float*)d_in[18];

    const int N  = in_sizes[0] / 128;  // 200000
    const int E  = in_sizes[1] / 2;    // 3200000
    const int NG = N / NPG;            // 2000
    const int NBIN = (N + CMASK) >> CSHIFT;  // 196
    const int* esrc = edge;
    const int* edst = edge + E;

    char* w = (char*)d_ws;
    auto alloc = [&](size_t bytes) -> void* {
        void* p = (void*)w;
        w += (bytes + 255) & ~(size_t)255;
        return p;
    };
    float* bufA    = (float*)alloc((size_t)N * HID * 4);   // holds bf16 g (first half) or fp32
    int*   csr     = (int*)alloc((size_t)E * 4);
    int*   row_ptr = (int*)alloc((size_t)(N + 1) * 4);
    int*   cnt     = (int*)alloc((size_t)N * 4);
    float* dinv    = (float*)alloc((size_t)N * 4);
    int*   partials= (int*)alloc(1024);
    float* emb     = (float*)alloc((size_t)NG * HID * 4);
    float* tbuf    = (float*)alloc((size_t)NG * HID * 4);
    int*   gcur    = (int*)alloc((size_t)NBIN * 16 * 4);
    int*   stage   = (int*)alloc((size_t)NBIN * SLOT * 4);

    float* B1 = (float*)d_out;                    // first half of d_out as scratch
    float* B2 = (float*)d_out + (size_t)N * HID;  // second half

    const int NB = (N + 2047) / 2048;
    const int GB = 1024;  // gemm blocks (4 waves each)

    // CSR build: LDS-binned two-phase, no random global atomics
    zero_int_kernel<<<(NBIN * 16 + 255) / 256, 256, 0, stream>>>(gcur, NBIN * 16);
    bin1_kernel<<<(E + TILE - 1) / TILE, 256, 0, stream>>>(esrc, edst, gcur, stage, E, NBIN);
    bin_count_kernel<<<NBIN, 256, 0, stream>>>(gcur, stage, cnt, dinv, N);
    scan1_kernel<<<NB, 256, 0, stream>>>(cnt, row_ptr, partials, N);
    scan2_kernel<<<1, 128, 0, stream>>>(partials, NB);
    scan3_kernel<<<NB, 256, 0, stream>>>(row_ptr, partials, N, E);
    bin_fill_kernel<<<NBIN, 256, 0, stream>>>(gcur, stage, row_ptr, csr, N);

    // encoder (GEMM writes packed bf16 g; agg gathers 128B rows, fp32 accumulate)
    mfma_gemm<128, 64, 1, false, true><<<GB, 256, 0, stream>>>(x, enc_W1, nullptr, dinv, bufA, N);
    agg_kernel<<<(N + 31) / 32, 256, 0, stream>>>((const unsigned*)bufA, row_ptr, csr, dinv, enc_b1, B1, N, 1);
    mfma_gemm<64, 64, 1, false, true><<<GB, 256, 0, stream>>>(B1, enc_W2, nullptr, dinv, bufA, N);
    agg_kernel<<<(N + 31) / 32, 256, 0, stream>>>((const unsigned*)bufA, row_ptr, csr, dinv, enc_b2, B1, N, 1);
    mfma_gemm<64, 64, 1, false, true><<<GB, 256, 0, stream>>>(B1, enc_W3, nullptr, dinv, bufA, N);
    agg_kernel<<<(N + 31) / 32, 256, 0, stream>>>((const unsigned*)bufA, row_ptr, csr, dinv, enc_b3, B1, N, 0);

    // pooling + decoder head
    pool_kernel<<<(NG * 64 + 255) / 256, 256, 0, stream>>>(B1, emb, NG);
    decinit_kernel<<<(NG * 64 + 255) / 256, 256, 0, stream>>>(emb, dec_Wt, dec_bt, dec_W1, tbuf, NG);
    z1_kernel<<<(N * 16 + 255) / 256, 256, 0, stream>>>(tbuf, dec_b1, B1, N);

    // decoder stencil layers (fp32 path unchanged)
    mfma_gemm<64, 64, 2, false, false><<<GB, 256, 0, stream>>>(B1, dec_W2, nullptr, nullptr, bufA, N);
    stencil_kernel<<<NG, 256, 0, stream>>>(bufA, dec_b2, B1, NG);
    mfma_gemm<64, 64, 2, false, false><<<GB, 256, 0, stream>>>(B1, dec_W3, nullptr, nullptr, B2, N);
    stencil_kernel<<<NG, 256, 0, stream>>>(B2, dec_b3, bufA, NG);

    // output projection
    mfma_gemm<64, 128, 0, true, false><<<GB, 256, 0, stream>>>(bufA, out_W, out_b, nullptr,
                                                               (float*)d_out, N);
}

// Round 7
// 479.507 us; speedup vs baseline: 1.9850x; 1.1320x over previous
//
#include <hip/hip_runtime.h>
#include <hip/hip_bf16.h>
#include <cstdint>

#define HID 64
#define NPG 100

// coarse buckets for CSR build: 1024 dsts per bucket
#define CSHIFT 10
#define CMASK ((1 << CSHIFT) - 1)
#define CAP 56          // LDS slots per bin per tile (λ≈42, spill ~1%)
#define TILE 8192       // edges per phase-1 block
#define SLOT 32768      // staging ints per bucket (mean ~16.6k, 2x slack)

typedef short bf16x8 __attribute__((ext_vector_type(8)));
typedef float f32x4 __attribute__((ext_vector_type(4)));
typedef float f32x2 __attribute__((ext_vector_type(2)));

__device__ __forceinline__ unsigned short bf16_rn(float f) {
    union { float f; unsigned u; } c; c.f = f;
    unsigned r = c.u + 0x7fffu + ((c.u >> 16) & 1u);
    return (unsigned short)(r >> 16);
}
__device__ __forceinline__ float bf16_f(unsigned short h) {
    union { unsigned u; float f; } c; c.u = ((unsigned)h) << 16;
    return c.f;
}

// decoder chain-graph degree
__device__ __forceinline__ float dinvdec(int p) {
    int d = (p >= 1) + (p >= 2) + (p <= NPG - 2) + (p <= NPG - 3);
    return rsqrtf((float)(d + 1));
}

// ---------------- CSR build (LDS-binned, no cross-XCD line sharing) ----------------

__global__ void zero_int_kernel(int* __restrict__ p, int n) {
    int i = blockIdx.x * 256 + threadIdx.x;
    if (i < n) p[i] = 0;
}

// Phase 1: block-private tile -> LDS bins -> chunked flush (one padded atomic per bin).
__global__ __launch_bounds__(256) void bin1_kernel(const int* __restrict__ src,
                                                   const int* __restrict__ dst,
                                                   int* __restrict__ gcur,
                                                   int* __restrict__ stage,
                                                   int E, int nbin) {
    __shared__ int bins[256][CAP];
    __shared__ int bcnt[256];
    const int tid = threadIdx.x;
    bcnt[tid] = 0;
    __syncthreads();

    const int e0 = blockIdx.x * TILE;
    const int cnt = min(TILE, E - e0);
    for (int i = tid; i < cnt; i += 256) {
        int s = src[e0 + i], d = dst[e0 + i];
        int b = d >> CSHIFT;
        int v = (s << CSHIFT) | (d & CMASK);
        int pos = atomicAdd(&bcnt[b], 1);
        if (pos < CAP) {
            bins[b][pos] = v;
        } else {  // rare spill: private 4-slot chunk, -1 pads
            int g = atomicAdd(&gcur[b * 16], 4);
            int* sp = stage + (size_t)b * SLOT + g;
            sp[0] = v; sp[1] = -1; sp[2] = -1; sp[3] = -1;
        }
    }
    __syncthreads();

    if (tid < nbin) {
        int c = min(bcnt[tid], CAP);
        int r = (c + 3) & ~3;
        if (r > 0) {
            int base = atomicAdd(&gcur[tid * 16], r);
            int* dstp = stage + (size_t)tid * SLOT + base;
            for (int j = 0; j < r; j += 4) {
                int4 v;
                v.x = (j + 0 < c) ? bins[tid][j + 0] : -1;
                v.y = (j + 1 < c) ? bins[tid][j + 1] : -1;
                v.z = (j + 2 < c) ? bins[tid][j + 2] : -1;
                v.w = (j + 3 < c) ? bins[tid][j + 3] : -1;
                *(int4*)(dstp + j) = v;
            }
        }
    }
}

// Phase 2a: per-bucket degree count (LDS) -> coalesced cnt + dinv writes.
__global__ __launch_bounds__(256) void bin_count_kernel(const int* __restrict__ gcur,
                                                        const int* __restrict__ stage,
                                                        int* __restrict__ cntg,
                                                        float* __restrict__ dinvg, int N) {
    __shared__ int lc[1 << CSHIFT];
    const int b = blockIdx.x;
    for (int j = threadIdx.x; j < (1 << CSHIFT); j += 256) lc[j] = 0;
    __syncthreads();
    const int len = gcur[b * 16];
    const int* sp = stage + (size_t)b * SLOT;
    for (int i = threadIdx.x; i < len; i += 256) {
        int v = sp[i];
        if (v >= 0) atomicAdd(&lc[v & CMASK], 1);
    }
    __syncthreads();
    const int d0 = b << CSHIFT;
    for (int j = threadIdx.x; j < (1 << CSHIFT); j += 256) {
        int d = d0 + j;
        if (d < N) {
            int c = lc[j];
            cntg[d] = c;
            dinvg[d] = rsqrtf((float)c + 1.0f);
        }
    }
}

// block scans 2048 ints (256 thr x 8)
__global__ __launch_bounds__(256) void scan1_kernel(const int* __restrict__ cnt,
                                                    int* __restrict__ row_ptr,
                                                    int* __restrict__ partials, int N) {
    __shared__ int sd[256];
    int tid = threadIdx.x;
    int base = blockIdx.x * 2048 + tid * 8;
    int v[8];
    int s = 0;
#pragma unroll
    for (int j = 0; j < 8; j++) {
        int i = base + j;
        int t = (i < N) ? cnt[i] : 0;
        v[j] = t; s += t;
    }
    sd[tid] = s;
    __syncthreads();
    for (int off = 1; off < 256; off <<= 1) {
        int t = (tid >= off) ? sd[tid - off] : 0;
        __syncthreads();
        sd[tid] += t;
        __syncthreads();
    }
    int run = sd[tid] - s;  // exclusive within block
#pragma unroll
    for (int j = 0; j < 8; j++) {
        int i = base + j;
        if (i < N) row_ptr[i] = run;
        run += v[j];
    }
    if (tid == 0) partials[blockIdx.x] = sd[255];
}

__global__ void scan2_kernel(int* __restrict__ partials, int nb) {
    __shared__ int sd[128];
    int tid = threadIdx.x;
    int v = (tid < nb) ? partials[tid] : 0;
    sd[tid] = v;
    __syncthreads();
    for (int off = 1; off < 128; off <<= 1) {
        int t = (tid >= off) ? sd[tid - off] : 0;
        __syncthreads();
        sd[tid] += t;
        __syncthreads();
    }
    if (tid < nb) partials[tid] = sd[tid] - v;
}

__global__ void scan3_kernel(int* __restrict__ row_ptr, const int* __restrict__ partials,
                             int N, int E) {
    int base = blockIdx.x * 2048 + threadIdx.x * 8;
    int add = partials[blockIdx.x];
#pragma unroll
    for (int j = 0; j < 8; j++) {
        int i = base + j;
        if (i < N) row_ptr[i] += add;
    }
    if (blockIdx.x == 0 && threadIdx.x == 0) row_ptr[N] = E;
}

// Phase 2b: per-bucket scatter into exclusive L2-resident CSR window, LDS cursors.
__global__ __launch_bounds__(256) void bin_fill_kernel(const int* __restrict__ gcur,
                                                       const int* __restrict__ stage,
                                                       const int* __restrict__ row_ptr,
                                                       int* __restrict__ csr_src, int N) {
    __shared__ int cur[1 << CSHIFT];
    __shared__ int rp[1 << CSHIFT];
    const int b = blockIdx.x;
    const int d0 = b << CSHIFT;
    for (int j = threadIdx.x; j < (1 << CSHIFT); j += 256) {
        cur[j] = 0;
        int d = d0 + j;
        rp[j] = (d < N) ? row_ptr[d] : 0;
    }
    __syncthreads();
    const int len = gcur[b * 16];
    const int* sp = stage + (size_t)b * SLOT;
    for (int i = threadIdx.x; i < len; i += 256) {
        int v = sp[i];
        if (v >= 0) {
            int dl = v & CMASK;
            int pos = rp[dl] + atomicAdd(&cur[dl], 1);
            csr_src[pos] = v >> CSHIFT;
        }
    }
}

// ---------------- MFMA GEMM ----------------
// AMODE: 0 = fp32 A (convert in-reg), 1 = packed bf16 A.
// WP: 1 = plain bf16 W (1 MFMA), 2 = hi/lo split W+A (3 MFMA, fp32-grade).
// OMODE: 0 = fp32 out, 2 = packed fp8 e4m3 out.
template <int K, int N, int SCALE_MODE, bool BIAS, int AMODE, int WP, int OMODE>
__global__ __launch_bounds__(256, 2) void mfma_gemm(const float* __restrict__ A,
                                                    const float* __restrict__ W,
                                                    const float* __restrict__ bias,
                                                    const float* __restrict__ rowscale,
                                                    float* __restrict__ out, int M) {
    constexpr int KP = K + 8;
    constexpr int NT = N / 16;
    constexpr int KS = K / 32;
    __shared__ unsigned short Wt[WP][N][KP];
    const int tid = threadIdx.x;

    for (int idx = tid; idx < K * N; idx += 256) {
        float w = W[idx];
        int k = idx / N, n = idx % N;  // N is pow2
        unsigned short h = bf16_rn(w);
        Wt[0][n][k] = h;
        if (WP == 2) Wt[1][n][k] = bf16_rn(w - bf16_f(h));
    }
    __syncthreads();

    const int lane = tid & 63;
    const int l15 = lane & 15;
    const int lg = lane >> 4;  // 0..3
    const int nstrips = M / 16;
    const int wglobal = blockIdx.x * 4 + (tid >> 6);
    const int wtotal = gridDim.x * 4;

    float curf[AMODE == 0 ? KS * 8 : 1], nxtf[AMODE == 0 ? KS * 8 : 1];
    uint4 curv[AMODE == 1 ? KS : 1], nxtv[AMODE == 1 ? KS : 1];

    auto loadA_f = [&](int s, float* dstv) {
        const float* arow = A + (size_t)(s * 16 + l15) * K + lg * 8;
#pragma unroll
        for (int ks = 0; ks < KS; ks++) {
            float4 a = *(const float4*)(arow + ks * 32);
            float4 b = *(const float4*)(arow + ks * 32 + 4);
            dstv[ks * 8 + 0] = a.x; dstv[ks * 8 + 1] = a.y;
            dstv[ks * 8 + 2] = a.z; dstv[ks * 8 + 3] = a.w;
            dstv[ks * 8 + 4] = b.x; dstv[ks * 8 + 5] = b.y;
            dstv[ks * 8 + 6] = b.z; dstv[ks * 8 + 7] = b.w;
        }
    };
    auto loadA_h = [&](int s, uint4* dstv) {
        const unsigned short* arow = (const unsigned short*)A + (size_t)(s * 16 + l15) * K + lg * 8;
#pragma unroll
        for (int ks = 0; ks < KS; ks++)
            dstv[ks] = *(const uint4*)(arow + ks * 32);
    };

    int s = wglobal;
    if (s < nstrips) { if (AMODE == 0) loadA_f(s, curf); else loadA_h(s, curv); }
    for (; s < nstrips; s += wtotal) {
        int sn = s + wtotal;
        if (sn < nstrips) { if (AMODE == 0) loadA_f(sn, nxtf); else loadA_h(sn, nxtv); }

        f32x4 acc[NT];
#pragma unroll
        for (int t = 0; t < NT; t++) acc[t] = f32x4{0.f, 0.f, 0.f, 0.f};

#pragma unroll
        for (int ks = 0; ks < KS; ks++) {
            bf16x8 ah, al;
            if (AMODE == 1) {
                ah = *(bf16x8*)&curv[ks];
            } else {
#pragma unroll
                for (int j = 0; j < 8; j++) {
                    float v = curf[ks * 8 + j];
                    unsigned short h = bf16_rn(v);
                    ah[j] = (short)h;
                    if (WP == 2) al[j] = (short)bf16_rn(v - bf16_f(h));
                }
            }
            const int k0 = ks * 32 + lg * 8;
#pragma unroll
            for (int t = 0; t < NT; t++) {
                int n = t * 16 + l15;
                bf16x8 bh = *(const bf16x8*)&Wt[0][n][k0];
                acc[t] = __builtin_amdgcn_mfma_f32_16x16x32_bf16(ah, bh, acc[t], 0, 0, 0);
                if (WP == 2) {
                    bf16x8 bl = *(const bf16x8*)&Wt[1][n][k0];
                    acc[t] = __builtin_amdgcn_mfma_f32_16x16x32_bf16(ah, bl, acc[t], 0, 0, 0);
                    acc[t] = __builtin_amdgcn_mfma_f32_16x16x32_bf16(al, bh, acc[t], 0, 0, 0);
                }
            }
        }

#pragma unroll
        for (int r = 0; r < 4; r++) {
            int row = s * 16 + lg * 4 + r;
            float scale = 1.0f;
            if (SCALE_MODE == 1) scale = rowscale[row];
            if (SCALE_MODE == 2) scale = dinvdec(row % NPG);
#pragma unroll
            for (int t = 0; t < NT; t++) {
                float o = acc[t][r] * scale;
                if (BIAS) o += bias[t * 16 + l15];
                if (OMODE == 2) {
                    int p = __builtin_amdgcn_cvt_pk_fp8_f32(o, 0.0f, 0, false);
                    ((unsigned char*)out)[(size_t)row * N + t * 16 + l15] = (unsigned char)(p & 0xff);
                } else {
                    out[(size_t)row * N + t * 16 + l15] = o;
                }
            }
        }
        if (AMODE == 0) {
#pragma unroll
            for (int i = 0; i < KS * 8; i++) curf[i] = nxtf[i];
        } else {
#pragma unroll
            for (int i = 0; i < KS; i++) curv[i] = nxtv[i];
        }
    }
}

// ---------------- encoder aggregation (gather over CSR, fp8 rows) ----------------
// g is packed fp8 e4m3 [N][64] = 64B/row. 4 lanes/row (uint4 = 16 fp8 per lane),
// 64 rows per 256-thread block; 8-deep pipeline; fp32 accumulate; bf16 output.
__global__ __launch_bounds__(256) void agg_kernel(const unsigned int* __restrict__ g,
                                                  const int* __restrict__ row_ptr,
                                                  const int* __restrict__ csr_src,
                                                  const float* __restrict__ dinv,
                                                  const float* __restrict__ bias,
                                                  unsigned short* __restrict__ out,
                                                  int N, int do_relu) {
    const int tid = threadIdx.x;
    const int sub = tid >> 2;        // 0..63: row within block
    const int lg = tid & 3;          // 16B group (16 fp8 values)
    const int row = blockIdx.x * 64 + sub;
    if (row >= N) return;

    const uint4* g4 = (const uint4*)g;
    float acc[16] = {};

#define D4(u, i0) do { \
    f32x2 lo = __builtin_amdgcn_cvt_pk_f32_fp8((int)(u), false); \
    f32x2 hi = __builtin_amdgcn_cvt_pk_f32_fp8((int)(u), true); \
    acc[i0 + 0] += lo[0]; acc[i0 + 1] += lo[1]; \
    acc[i0 + 2] += hi[0]; acc[i0 + 3] += hi[1]; } while (0)
#define ACCV(vv) do { D4(vv.x, 0); D4(vv.y, 4); D4(vv.z, 8); D4(vv.w, 12); } while (0)

    {   // self term
        uint4 v = g4[(size_t)row * 4 + lg];
        ACCV(v);
    }

    const int s = row_ptr[row];
    const int e = row_ptr[row + 1];
    int j = s;

    for (; j + 8 <= e; j += 8) {
        int idx[8];
#pragma unroll
        for (int t = 0; t < 8; t++) idx[t] = csr_src[j + t];
        uint4 v[8];
#pragma unroll
        for (int t = 0; t < 8; t++) v[t] = g4[(size_t)idx[t] * 4 + lg];
#pragma unroll
        for (int t = 0; t < 8; t++) ACCV(v[t]);
    }
    for (; j + 2 <= e; j += 2) {
        int i0 = csr_src[j + 0], i1 = csr_src[j + 1];
        uint4 v0 = g4[(size_t)i0 * 4 + lg];
        uint4 v1 = g4[(size_t)i1 * 4 + lg];
        ACCV(v0); ACCV(v1);
    }
    if (j < e) {
        uint4 v = g4[(size_t)csr_src[j] * 4 + lg];
        ACCV(v);
    }
#undef ACCV
#undef D4

    const float d = dinv[row];
    unsigned ow[8];
#pragma unroll
    for (int i = 0; i < 8; i++) {
        float a = d * acc[2 * i] + bias[lg * 16 + 2 * i];
        float b = d * acc[2 * i + 1] + bias[lg * 16 + 2 * i + 1];
        if (do_relu) { a = fmaxf(a, 0.0f); b = fmaxf(b, 0.0f); }
        ow[i] = (unsigned)bf16_rn(a) | ((unsigned)bf16_rn(b) << 16);
    }
    uint4* o = (uint4*)(out + (size_t)row * HID + lg * 16);
    o[0] = *(uint4*)&ow[0];
    o[1] = *(uint4*)&ow[4];
}

// ---------------- pooling: mean over each graph's 100 rows (bf16 input) ----------------
__global__ void pool_kernel(const unsigned short* __restrict__ h, float* __restrict__ emb, int NG) {
    int wid = (blockIdx.x * 256 + threadIdx.x) >> 6;
    int lane = threadIdx.x & 63;
    if (wid >= NG) return;
    const unsigned short* base = h + (size_t)wid * NPG * HID + lane;
    float acc = 0.0f;
    for (int i = 0; i < NPG; i++) acc += bf16_f(base[i * HID]);
    emb[wid * HID + lane] = acc * (1.0f / NPG);
}

// ---------------- decoder init: t = (emb@Wt + bt) @ W1, one wave per graph ----------------
__global__ void decinit_kernel(const float* __restrict__ emb, const float* __restrict__ Wt,
                               const float* __restrict__ bt, const float* __restrict__ W1,
                               float* __restrict__ t, int NG) {
    int wid = (blockIdx.x * 256 + threadIdx.x) >> 6;
    int lane = threadIdx.x & 63;
    if (wid >= NG) return;
    float e = emb[wid * HID + lane];
    float acc = bt[lane];
    for (int k = 0; k < HID; k++) acc += __shfl(e, k) * Wt[k * HID + lane];
    float tv = 0.0f;
    for (int k = 0; k < HID; k++) tv += __shfl(acc, k) * W1[k * HID + lane];
    t[wid * HID + lane] = tv;
}

// ---------------- decoder layer 1: z1[i] = relu(t[graph]*s[pos] + b1) ----------------
__global__ void z1_kernel(const float* __restrict__ t, const float* __restrict__ b1,
                          float* __restrict__ out, int N) {
    int i4 = blockIdx.x * 256 + threadIdx.x;
    if (i4 >= N * (HID / 4)) return;
    int row = i4 >> 4, c4 = i4 & 15;
    int gph = row / NPG;
    int p = row - gph * NPG;
    float dp = dinvdec(p);
    float qs = dp;
    if (p >= 1) qs += dinvdec(p - 1);
    if (p >= 2) qs += dinvdec(p - 2);
    if (p <= NPG - 2) qs += dinvdec(p + 1);
    if (p <= NPG - 3) qs += dinvdec(p + 2);
    float s = dp * qs;
    float4 tv = ((const float4*)t)[gph * (HID / 4) + c4];
    float4 bv = ((const float4*)b1)[c4];
    float4 o;
    o.x = fmaxf(s * tv.x + bv.x, 0.0f);
    o.y = fmaxf(s * tv.y + bv.y, 0.0f);
    o.z = fmaxf(s * tv.z + bv.z, 0.0f);
    o.w = fmaxf(s * tv.w + bv.w, 0.0f);
    ((float4*)out)[i4] = o;
}

// ---------------- decoder stencil layers (one block per graph) ----------------
__global__ __launch_bounds__(256) void stencil_kernel(const float* __restrict__ g,
                                                      const float* __restrict__ bias,
                                                      float* __restrict__ out, int NG) {
    __shared__ float gs[NPG * HID];
    int gph = blockIdx.x;
    const float4* src = (const float4*)(g + (size_t)gph * NPG * HID);
    for (int idx = threadIdx.x; idx < NPG * HID / 4; idx += 256)
        ((float4*)gs)[idx] = src[idx];
    __syncthreads();
    int c = threadIdx.x & 63;
    for (int p = threadIdx.x >> 6; p < NPG; p += 4) {
        float acc = gs[p * HID + c];
        if (p >= 1) acc += gs[(p - 1) * HID + c];
        if (p >= 2) acc += gs[(p - 2) * HID + c];
        if (p <= NPG - 2) acc += gs[(p + 1) * HID + c];
        if (p <= NPG - 3) acc += gs[(p + 2) * HID + c];
        float v = dinvdec(p) * acc + bias[c];
        v = fmaxf(v, 0.0f);
        out[(size_t)(gph * NPG + p) * HID + c] = v;
    }
}

// ---------------- launch ----------------

extern "C" void kernel_launch(void* const* d_in, const int* in_sizes, int n_in,
                              void* d_out, int out_size, void* d_ws, size_t ws_size,
                              hipStream_t stream) {
    const float* x      = (const float*)d_in[0];
    const int*   edge   = (const int*)d_in[1];
    const float* enc_W1 = (const float*)d_in[3];
    const float* enc_b1 = (const float*)d_in[4];
    const float* enc_W2 = (const float*)d_in[5];
    const float* enc_b2 = (const float*)d_in[6];
    const float* enc_W3 = (const float*)d_in[7];
    const float* enc_b3 = (const float*)d_in[8];
    const float* dec_Wt = (const float*)d_in[9];
    const float* dec_bt = (const float*)d_in[10];
    const float* dec_W1 = (const float*)d_in[11];
    const float* dec_b1 = (const float*)d_in[12];
    const float* dec_W2 = (const float*)d_in[13];
    const float* dec_b2 = (const float*)d_in[14];
    const float* dec_W3 = (const float*)d_in[15];
    const float* dec_b3 = (const float*)d_in[16];
    const float* out_W  = (const float*)d_in[17];
    const float* out_b  = (const float*)d_in[18];

    const int N  = in_sizes[0] / 128;  // 200000
    const int E  = in_sizes[1] / 2;    // 3200000
    const int NG = N / NPG;            // 2000
    const int NBIN = (N + CMASK) >> CSHIFT;  // 196
    const int* esrc = edge;
    const int* edst = edge + E;

    char* w = (char*)d_ws;
    auto alloc = [&](size_t bytes) -> void* {
        void* p = (void*)w;
        w += (bytes + 255) & ~(size_t)255;
        return p;
    };
    float* bufA    = (float*)alloc((size_t)N * HID * 4);   // fp8 g (encoder) / fp32 (decoder)
    int*   csr     = (int*)alloc((size_t)E * 4);
    int*   row_ptr = (int*)alloc((size_t)(N + 1) * 4);
    int*   cnt     = (int*)alloc((size_t)N * 4);
    float* dinv    = (float*)alloc((size_t)N * 4);
    int*   partials= (int*)alloc(1024);
    float* emb     = (float*)alloc((size_t)NG * HID * 4);
    float* tbuf    = (float*)alloc((size_t)NG * HID * 4);
    int*   gcur    = (int*)alloc((size_t)NBIN * 16 * 4);
    int*   stage   = (int*)alloc((size_t)NBIN * SLOT * 4);

    float* B1 = (float*)d_out;                    // first half of d_out as scratch
    float* B2 = (float*)d_out + (size_t)N * HID;  // second half

    const int NB = (N + 2047) / 2048;
    const int GB = 1024;  // gemm blocks (4 waves each)

    // CSR build: LDS-binned two-phase, no random global atomics
    zero_int_kernel<<<(NBIN * 16 + 255) / 256, 256, 0, stream>>>(gcur, NBIN * 16);
    bin1_kernel<<<(E + TILE - 1) / TILE, 256, 0, stream>>>(esrc, edst, gcur, stage, E, NBIN);
    bin_count_kernel<<<NBIN, 256, 0, stream>>>(gcur, stage, cnt, dinv, N);
    scan1_kernel<<<NB, 256, 0, stream>>>(cnt, row_ptr, partials, N);
    scan2_kernel<<<1, 128, 0, stream>>>(partials, NB);
    scan3_kernel<<<NB, 256, 0, stream>>>(row_ptr, partials, N, E);
    bin_fill_kernel<<<NBIN, 256, 0, stream>>>(gcur, stage, row_ptr, csr, N);

    // encoder: GEMM (bf16 math) -> fp8 g; agg gathers 64B fp8 rows -> bf16 h
    mfma_gemm<128, 64, 1, false, 0, 1, 2><<<GB, 256, 0, stream>>>(x, enc_W1, nullptr, dinv, bufA, N);
    agg_kernel<<<(N + 63) / 64, 256, 0, stream>>>((const unsigned*)bufA, row_ptr, csr, dinv, enc_b1,
                                                  (unsigned short*)B1, N, 1);
    mfma_gemm<64, 64, 1, false, 1, 1, 2><<<GB, 256, 0, stream>>>(B1, enc_W2, nullptr, dinv, bufA, N);
    agg_kernel<<<(N + 63) / 64, 256, 0, stream>>>((const unsigned*)bufA, row_ptr, csr, dinv, enc_b2,
                                                  (unsigned short*)B1, N, 1);
    mfma_gemm<64, 64, 1, false, 1, 1, 2><<<GB, 256, 0, stream>>>(B1, enc_W3, nullptr, dinv, bufA, N);
    agg_kernel<<<(N + 63) / 64, 256, 0, stream>>>((const unsigned*)bufA, row_ptr, csr, dinv, enc_b3,
                                                  (unsigned short*)B1, N, 0);

    // pooling + decoder head
    pool_kernel<<<(NG * 64 + 255) / 256, 256, 0, stream>>>((const unsigned short*)B1, emb, NG);
    decinit_kernel<<<(NG * 64 + 255) / 256, 256, 0, stream>>>(emb, dec_Wt, dec_bt, dec_W1, tbuf, NG);
    z1_kernel<<<(N * 16 + 255) / 256, 256, 0, stream>>>(tbuf, dec_b1, B1, N);

    // decoder stencil layers (fp32-grade path unchanged)
    mfma_gemm<64, 64, 2, false, 0, 2, 0><<<GB, 256, 0, stream>>>(B1, dec_W2, nullptr, nullptr, bufA, N);
    stencil_kernel<<<NG, 256, 0, stream>>>(bufA, dec_b2, B1, NG);
    mfma_gemm<64, 64, 2, false, 0, 2, 0><<<GB, 256, 0, stream>>>(B1, dec_W3, nullptr, nullptr, B2, N);
    stencil_kernel<<<NG, 256, 0, stream>>>(B2, dec_b3, bufA, NG);

    // output projection
    mfma_gemm<64, 128, 0, true, 0, 2, 0><<<GB, 256, 0, stream>>>(bufA, out_W, out_b, nullptr,
                                                                 (float*)d_out, N);
}